// Round 5
// baseline (18100.331 us; speedup 1.0000x reference)
//
#include <hip/hip_runtime.h>
#include <hip/hip_bf16.h>

#define L_SEQ 2048
#define HDIM 512
#define NGATE4 2048   // 4*HD
#define TAGS 48
#define START_TAG 46
#define STOP_TAG 47
#define NWG 16        // workgroups per direction in lstm_layer

typedef float4 f4;

// ---------------------------------------------------------------------------
// GEMM: C[M,N] = A[M,K] @ B[N,K]^T + bias1[n] (+ bias2[n])
// A rows optionally gathered: row m -> A + gather[m]*K (embedding lookup).
// f32 vector-ALU (no f32 MFMA on CDNA4). 64x64 tile, BK=32, 256 threads, 4x4/thread.
// ---------------------------------------------------------------------------
#define BM 64
#define BN 64
#define BK 32
#define LDT 68   // padded LDS row stride (floats)

__global__ __launch_bounds__(256, 2)
void gemm_abt(const float* __restrict__ A, const float* __restrict__ B,
              const float* __restrict__ bias1, const float* __restrict__ bias2,
              float* __restrict__ C, int M, int N, int K,
              const int* __restrict__ gather)
{
  __shared__ float As[BK][LDT];
  __shared__ float Bs[BK][LDT];
  const int tid = threadIdx.x;
  const int m0 = blockIdx.x * BM;
  const int n0 = blockIdx.y * BN;
  const int tm = tid >> 4, tn = tid & 15;
  const int lr = tid >> 2, lk = (tid & 3) * 8;

  float acc[4][4];
#pragma unroll
  for (int i = 0; i < 4; ++i)
#pragma unroll
    for (int c = 0; c < 4; ++c) acc[i][c] = 0.f;

  const int am = m0 + lr;
  const float* arow = gather ? (A + (size_t)gather[am] * (size_t)K)
                             : (A + (size_t)am * (size_t)K);
  const int bn = n0 + lr;
  const float* brow = B + (size_t)bn * (size_t)K;
  const bool bok = (bn < N);

  for (int kt = 0; kt < K; kt += BK) {
    const float4 a0 = *(const float4*)(arow + kt + lk);
    const float4 a1 = *(const float4*)(arow + kt + lk + 4);
    float4 b0 = make_float4(0.f, 0.f, 0.f, 0.f);
    float4 b1 = make_float4(0.f, 0.f, 0.f, 0.f);
    if (bok) {
      b0 = *(const float4*)(brow + kt + lk);
      b1 = *(const float4*)(brow + kt + lk + 4);
    }
    As[lk + 0][lr] = a0.x; As[lk + 1][lr] = a0.y; As[lk + 2][lr] = a0.z; As[lk + 3][lr] = a0.w;
    As[lk + 4][lr] = a1.x; As[lk + 5][lr] = a1.y; As[lk + 6][lr] = a1.z; As[lk + 7][lr] = a1.w;
    Bs[lk + 0][lr] = b0.x; Bs[lk + 1][lr] = b0.y; Bs[lk + 2][lr] = b0.z; Bs[lk + 3][lr] = b0.w;
    Bs[lk + 4][lr] = b1.x; Bs[lk + 5][lr] = b1.y; Bs[lk + 6][lr] = b1.z; Bs[lk + 7][lr] = b1.w;
    __syncthreads();
#pragma unroll
    for (int kk = 0; kk < BK; ++kk) {
      const float4 av = *(const float4*)&As[kk][tm * 4];
      const float4 bv = *(const float4*)&Bs[kk][tn * 4];
      const float aa[4] = {av.x, av.y, av.z, av.w};
      const float bb[4] = {bv.x, bv.y, bv.z, bv.w};
#pragma unroll
      for (int i = 0; i < 4; ++i)
#pragma unroll
        for (int c = 0; c < 4; ++c)
          acc[i][c] += aa[i] * bb[c];
    }
    __syncthreads();
  }

  float bsum[4];
#pragma unroll
  for (int c = 0; c < 4; ++c) {
    const int n = n0 + tn * 4 + c;
    float bb = 0.f;
    if (n < N) { bb = bias1[n]; if (bias2) bb += bias2[n]; }
    bsum[c] = bb;
  }
#pragma unroll
  for (int i = 0; i < 4; ++i) {
    const int m = m0 + tm * 4 + i;
#pragma unroll
    for (int c = 0; c < 4; ++c) {
      const int n = n0 + tn * 4 + c;
      if (n < N) C[(size_t)m * N + n] = acc[i][c] + bsum[c];
    }
  }
}

// ---------------------------------------------------------------------------
// Persistent bidirectional LSTM layer.
// 16 WGs x 512 threads per direction. Weights held in 32 NAMED float4 VGPRs
// per thread (promote-alloca refused the array form -> scratch; named
// variables cannot be demoted). Grid = 128, active iff blockIdx%8 < 2:
// dir0 WGs all land on XCD0, dir1 on XCD1 (blockIdx%8 round-robin heuristic).
// Sync: leaders store h (agent atomics); barrier; tid0 release-stores its
// monotonic slot; wave0 polls 16 slots lane-parallel with acquire loads.
// ---------------------------------------------------------------------------
#define LOADW(g) { const float* wr = whh + (size_t)((g) * HDIM + j) * HDIM + 32 * q; \
  w##g##0 = *(const f4*)(wr + 4 * ((0 + q) & 7)); \
  w##g##1 = *(const f4*)(wr + 4 * ((1 + q) & 7)); \
  w##g##2 = *(const f4*)(wr + 4 * ((2 + q) & 7)); \
  w##g##3 = *(const f4*)(wr + 4 * ((3 + q) & 7)); \
  w##g##4 = *(const f4*)(wr + 4 * ((4 + q) & 7)); \
  w##g##5 = *(const f4*)(wr + 4 * ((5 + q) & 7)); \
  w##g##6 = *(const f4*)(wr + 4 * ((6 + q) & 7)); \
  w##g##7 = *(const f4*)(wr + 4 * ((7 + q) & 7)); }

// NOTE: parameter names must not collide with member tokens .x/.y/.z/.w
#define FMA4(A_, W_, H_) { A_.x += (W_).x * (H_).x; A_.y += (W_).y * (H_).y; \
                           A_.z += (W_).z * (H_).z; A_.w += (W_).w * (H_).w; }

#define FI(i) { const f4 hv_ = *(const f4*)&h_lds[32 * q + 4 * (((i) + q) & 7)]; \
  FMA4(acc0, w0##i, hv_) FMA4(acc1, w1##i, hv_) FMA4(acc2, w2##i, hv_) FMA4(acc3, w3##i, hv_) }

__global__ __launch_bounds__(512, 1)
void lstm_layer(const float* __restrict__ pre_f, const float* __restrict__ pre_r,
                const float* __restrict__ whh_f, const float* __restrict__ whh_r,
                const float* __restrict__ h0, const float* __restrict__ c0,
                int hcrow_base,
                float* __restrict__ hs_out,   // [L][1024]
                int* __restrict__ slots)      // [2][NWG], zeroed before launch
{
  const int sel = blockIdx.x & 7;
  if (sel > 1) return;                 // 112 of 128 blocks retire instantly
  const int dir = sel;
  const int wg  = blockIdx.x >> 3;     // 0..15
  const float* pre = dir ? pre_r : pre_f;
  const float* whh = dir ? whh_r : whh_f;
  int* myslots = slots + dir * NWG;
  const int tid = threadIdx.x;
  const int lane = tid & 63;
  const int wave = tid >> 6;
  const int q = lane & 15;                 // k-chunk 0..15 (32 k each)
  const int jj = (wave << 2) | (lane >> 4);// 0..31
  const int j = wg * 32 + jj;              // owned h index
  const bool leader = (q == 0);
  const int hc = (hcrow_base + dir) * HDIM;

  __shared__ float h_lds[HDIM];

  // 32 named float4 = 128 VGPRs of W_hh per thread. k-window rotated by q:
  // bank index depends only on (i+q)&7 -> exactly 2-way LDS aliasing (free).
  f4 w00, w01, w02, w03, w04, w05, w06, w07;
  f4 w10, w11, w12, w13, w14, w15, w16, w17;
  f4 w20, w21, w22, w23, w24, w25, w26, w27;
  f4 w30, w31, w32, w33, w34, w35, w36, w37;
  LOADW(0) LOADW(1) LOADW(2) LOADW(3)

  h_lds[tid] = h0[hc + tid];               // blockDim == HDIM
  float cst = leader ? c0[hc + j] : 0.f;
  __syncthreads();

  // software-prefetched pre-activation values (one step ahead)
  float p0, p1, p2, p3;
  {
    const int t0 = dir ? (L_SEQ - 1) : 0;
    const float* pr = pre + (size_t)t0 * NGATE4 + j;
    p0 = leader ? pr[0 * HDIM] : 0.f;
    p1 = leader ? pr[1 * HDIM] : 0.f;
    p2 = leader ? pr[2 * HDIM] : 0.f;
    p3 = leader ? pr[3 * HDIM] : 0.f;
  }

  for (int s = 0; s < L_SEQ; ++s) {
    const int t = dir ? (L_SEQ - 1 - s) : s;
    float pn0 = 0.f, pn1 = 0.f, pn2 = 0.f, pn3 = 0.f;
    if (leader && (s + 1 < L_SEQ)) {
      const int tnx = dir ? (L_SEQ - 2 - s) : (s + 1);
      const float* pr = pre + (size_t)tnx * NGATE4 + j;
      pn0 = pr[0 * HDIM]; pn1 = pr[1 * HDIM];
      pn2 = pr[2 * HDIM]; pn3 = pr[3 * HDIM];
    }

    f4 acc0 = make_float4(0.f, 0.f, 0.f, 0.f);
    f4 acc1 = make_float4(0.f, 0.f, 0.f, 0.f);
    f4 acc2 = make_float4(0.f, 0.f, 0.f, 0.f);
    f4 acc3 = make_float4(0.f, 0.f, 0.f, 0.f);
    FI(0) FI(1) FI(2) FI(3) FI(4) FI(5) FI(6) FI(7)
    float a0 = acc0.x + acc0.y + acc0.z + acc0.w;
    float a1 = acc1.x + acc1.y + acc1.z + acc1.w;
    float a2 = acc2.x + acc2.y + acc2.z + acc2.w;
    float a3 = acc3.x + acc3.y + acc3.z + acc3.w;
#pragma unroll
    for (int m = 1; m < 16; m <<= 1) {
      a0 += __shfl_xor(a0, m, 64);
      a1 += __shfl_xor(a1, m, 64);
      a2 += __shfl_xor(a2, m, 64);
      a3 += __shfl_xor(a3, m, 64);
    }

    if (leader) {
      const float gi = p0 + a0;
      const float gf = p1 + a1;
      const float gg = p2 + a2;
      const float go = p3 + a3;
      const float si = 1.f / (1.f + __expf(-gi));
      const float sf = 1.f / (1.f + __expf(-gf));
      const float tg = 1.f - 2.f / (__expf(2.f * gg) + 1.f);
      const float so = 1.f / (1.f + __expf(-go));
      cst = sf * cst + si * tg;
      const float th = 1.f - 2.f / (__expf(2.f * cst) + 1.f);
      const float h = so * th;
      __hip_atomic_store(&hs_out[(size_t)t * 1024 + dir * HDIM + j], h,
                         __ATOMIC_RELAXED, __HIP_MEMORY_SCOPE_AGENT);
    }
    p0 = pn0; p1 = pn1; p2 = pn2; p3 = pn3;

    if (s == L_SEQ - 1) break;

    __syncthreads();   // drains this WG's h stores (vmcnt0 before barrier)
    if (tid == 0)
      __hip_atomic_store(&myslots[wg], s + 1, __ATOMIC_RELEASE,
                         __HIP_MEMORY_SCOPE_AGENT);
    if (wave == 0) {
      for (;;) {
        const int v = (lane < NWG)
            ? __hip_atomic_load(&myslots[lane], __ATOMIC_ACQUIRE,
                                __HIP_MEMORY_SCOPE_AGENT)
            : 0x7fffffff;
        if (__all(v > s)) break;
      }
    }
    __syncthreads();
    {
      const size_t base = (size_t)t * 1024 + dir * HDIM;
      h_lds[tid] = __hip_atomic_load(&hs_out[base + tid], __ATOMIC_RELAXED,
                                     __HIP_MEMORY_SCOPE_AGENT);
    }
    __syncthreads();
  }
}

// ---------------------------------------------------------------------------
// Viterbi: 1 WG, 192 threads = (48 tags) x (4 k-chunks of 12). Per step:
// chunk-local first-max chain, shfl argmax reduce over chunks (first-index
// tie-break matching jnp.argmax), fv via LDS. Backpointers to global ws;
// sequential backtrack at the end. Score -> out[0], path -> out[1..2048].
// ---------------------------------------------------------------------------
__global__ __launch_bounds__(192, 1)
void viterbi_kernel(const float* __restrict__ feats,
                    const float* __restrict__ trans,
                    int* __restrict__ bp,      // [L][48]
                    float* __restrict__ out)   // [1 + L]
{
  __shared__ float fv[TAGS];
  __shared__ float fvn[TAGS];
  const int tid = threadIdx.x;
  const int lane = tid & 63;
  const int wave = tid >> 6;
  const int q = lane & 3;
  const int j = wave * 16 + (lane >> 2);  // 0..47

  float trr[12];
#pragma unroll
  for (int kk = 0; kk < 12; ++kk) trr[kk] = trans[j * TAGS + q * 12 + kk];

  if (tid < TAGS) fv[tid] = (tid == START_TAG) ? 0.f : -10000.f;
  __syncthreads();

  for (int t = 0; t < L_SEQ; ++t) {
    const float ft = feats[t * TAGS + j];   // issued early, used post-reduce
    float best = -3.0e38f;
    int bi = 0;
#pragma unroll
    for (int kk = 0; kk < 12; ++kk) {
      const int k = q * 12 + kk;
      const float sc = fv[k] + trr[kk];
      if (sc > best) { best = sc; bi = k; }   // strict > keeps first max
    }
#pragma unroll
    for (int m = 1; m < 4; m <<= 1) {
      const float ov = __shfl_xor(best, m, 64);
      const int oi = __shfl_xor(bi, m, 64);
      if (ov > best || (ov == best && oi < bi)) { best = ov; bi = oi; }
    }
    __syncthreads();   // all fv reads done
    if (q == 0) {
      bp[t * TAGS + j] = bi;
      fv[j] = best + ft;
    }
    __syncthreads();
  }

  if (tid < TAGS) fvn[tid] = fv[tid] + trans[STOP_TAG * TAGS + tid];
  __syncthreads();
  if (tid == 0) {
    float best = -3.0e38f;
    int bi = 0;
    for (int k = 0; k < TAGS; ++k) {
      const float v = fvn[k];
      if (v > best) { best = v; bi = k; }
    }
    out[0] = best;
    int cur = bi;
    out[1 + (L_SEQ - 1)] = (float)cur;
    for (int t = L_SEQ - 2; t >= 0; --t) {
      cur = bp[(t + 1) * TAGS + cur];
      out[1 + t] = (float)cur;
    }
  }
}

// ---------------------------------------------------------------------------
extern "C" void kernel_launch(void* const* d_in, const int* in_sizes, int n_in,
                              void* d_out, int out_size, void* d_ws, size_t ws_size,
                              hipStream_t stream)
{
  const int*   sentence  = (const int*)  d_in[0];
  const float* embedding = (const float*)d_in[1];
  const float* w_ih_l0   = (const float*)d_in[2];
  const float* w_hh_l0   = (const float*)d_in[3];
  const float* b_ih_l0   = (const float*)d_in[4];
  const float* b_hh_l0   = (const float*)d_in[5];
  const float* w_ih_l0r  = (const float*)d_in[6];
  const float* w_hh_l0r  = (const float*)d_in[7];
  const float* b_ih_l0r  = (const float*)d_in[8];
  const float* b_hh_l0r  = (const float*)d_in[9];
  const float* w_ih_l1   = (const float*)d_in[10];
  const float* w_hh_l1   = (const float*)d_in[11];
  const float* b_ih_l1   = (const float*)d_in[12];
  const float* b_hh_l1   = (const float*)d_in[13];
  const float* w_ih_l1r  = (const float*)d_in[14];
  const float* w_hh_l1r  = (const float*)d_in[15];
  const float* b_ih_l1r  = (const float*)d_in[16];
  const float* b_hh_l1r  = (const float*)d_in[17];
  const float* h0        = (const float*)d_in[18];
  const float* c0        = (const float*)d_in[19];
  const float* W_tag     = (const float*)d_in[20];
  const float* b_tag     = (const float*)d_in[21];
  const float* trans     = (const float*)d_in[22];

  float* ws    = (float*)d_ws;
  float* pre_f = ws;                                  // [L][2048]
  float* pre_r = pre_f + (size_t)L_SEQ * NGATE4;      // [L][2048]
  float* l0out = pre_r + (size_t)L_SEQ * NGATE4;      // [L][1024]
  float* l1out = l0out + (size_t)L_SEQ * 1024;        // [L][1024]
  float* feats = l1out + (size_t)L_SEQ * 1024;        // [L][48]
  int*   slots = (int*)(feats + (size_t)L_SEQ * TAGS);// [2 layers][2][NWG]
  int*   bp    = slots + 4 * NWG;                     // [L][48]

  (void)hipMemsetAsync(slots, 0, 4 * NWG * sizeof(int), stream);

  dim3 blk(256);
  dim3 gfull(L_SEQ / BM, NGATE4 / BN);
  gemm_abt<<<gfull, blk, 0, stream>>>(embedding, w_ih_l0, b_ih_l0, b_hh_l0,
                                      pre_f, L_SEQ, NGATE4, 512, sentence);
  gemm_abt<<<gfull, blk, 0, stream>>>(embedding, w_ih_l0r, b_ih_l0r, b_hh_l0r,
                                      pre_r, L_SEQ, NGATE4, 512, sentence);
  lstm_layer<<<128, 512, 0, stream>>>(pre_f, pre_r, w_hh_l0, w_hh_l0r,
                                      h0, c0, 0, l0out, slots);
  gemm_abt<<<gfull, blk, 0, stream>>>(l0out, w_ih_l1, b_ih_l1, b_hh_l1,
                                      pre_f, L_SEQ, NGATE4, 1024, nullptr);
  gemm_abt<<<gfull, blk, 0, stream>>>(l0out, w_ih_l1r, b_ih_l1r, b_hh_l1r,
                                      pre_r, L_SEQ, NGATE4, 1024, nullptr);
  lstm_layer<<<128, 512, 0, stream>>>(pre_f, pre_r, w_hh_l1, w_hh_l1r,
                                      h0, c0, 2, l1out, slots + 2 * NWG);
  dim3 gfeat(L_SEQ / BM, 1);
  gemm_abt<<<gfeat, blk, 0, stream>>>(l1out, W_tag, b_tag, nullptr,
                                      feats, L_SEQ, TAGS, 1024, nullptr);
  viterbi_kernel<<<1, 192, 0, stream>>>(feats, trans, bp, (float*)d_out);
}